// Round 1
// baseline (50.949 us; speedup 1.0000x reference)
//
#include <hip/hip_runtime.h>

// ChiSquareLoss: per-image RGB 256-bin histograms of two [B,3,512,512] f32
// tensors in [0,1], normalized, chi-square distance summed over 768 bins,
// mean over batch.
//
// Layout facts (hard-wired to the reference shapes):
//   H*W = 262144 -> 65536 float4 per channel (HW4)
//   per image: 3*H*W = 786432 elems -> 196608 float4 (F4_PER_IMG)
//   normalization sum is EXACTLY 786432 per image (every pixel hits one bin).

#define NCH       3
#define BINS      256
#define HW4       65536      // (512*512)/4 float4 per channel
#define F4_PER_IMG (NCH * HW4)
#define BPI       48         // blocks per (input, image)
#define F4_PER_BLOCK (F4_PER_IMG / BPI)   // 4096, divides HW4 -> single channel per block
#define THREADS   256
#define F4_PER_THREAD (F4_PER_BLOCK / THREADS) // 16

__global__ __launch_bounds__(THREADS)
void hist_kernel(const float* __restrict__ in0,
                 const float* __restrict__ in1,
                 unsigned int* __restrict__ ghist,   // [2][B][768]
                 int B) {
    const int b = blockIdx.x;
    const int input = b / (B * BPI);
    const int rem   = b - input * (B * BPI);
    const int img   = rem / BPI;
    const int slice = rem - img * BPI;
    const int channel = slice >> 4;   // slice * 4096 / 65536

    const float4* __restrict__ src =
        (const float4*)(input ? in1 : in0);
    const size_t base = (size_t)img * F4_PER_IMG + (size_t)slice * F4_PER_BLOCK;

    // per-wave privatized histograms: 4 waves x 256 bins
    __shared__ unsigned int lhist[4][BINS];
    const int tid = threadIdx.x;
    const int w = tid >> 6;

    #pragma unroll
    for (int i = 0; i < 4; ++i)
        ((unsigned int*)lhist)[tid + i * THREADS] = 0u;
    __syncthreads();

    #pragma unroll
    for (int i = 0; i < F4_PER_THREAD; ++i) {
        float4 v = src[base + (size_t)i * THREADS + tid];
        // truncation == floor for non-negative; clamp handles v==1.0 and safety
        int b0 = (int)fminf(fmaxf(v.x * 255.0f, 0.0f), 255.0f);
        int b1 = (int)fminf(fmaxf(v.y * 255.0f, 0.0f), 255.0f);
        int b2 = (int)fminf(fmaxf(v.z * 255.0f, 0.0f), 255.0f);
        int b3 = (int)fminf(fmaxf(v.w * 255.0f, 0.0f), 255.0f);
        atomicAdd(&lhist[w][b0], 1u);
        atomicAdd(&lhist[w][b1], 1u);
        atomicAdd(&lhist[w][b2], 1u);
        atomicAdd(&lhist[w][b3], 1u);
    }
    __syncthreads();

    unsigned int s = lhist[0][tid] + lhist[1][tid] + lhist[2][tid] + lhist[3][tid];
    atomicAdd(&ghist[(((size_t)input * B + img) * NCH + channel) * BINS + tid], s);
}

__global__ __launch_bounds__(1024)
void chi_kernel(const unsigned int* __restrict__ ghist, float* __restrict__ out, int B) {
    const unsigned int* __restrict__ h1 = ghist;
    const unsigned int* __restrict__ h2 = ghist + (size_t)B * NCH * BINS;
    const int total = B * NCH * BINS;
    const float N = (float)(NCH * 512 * 512);   // 786432, exact per-image sum

    double acc = 0.0;
    for (int i = threadIdx.x; i < total; i += 1024) {
        float a1 = (float)h1[i] / N;
        float a2 = (float)h2[i] / N;
        float d = a1 - a2;
        float s = a1 + a2 + 1e-10f;
        acc += (double)(d * d / s);
    }

    // wave (64-lane) reduce
    #pragma unroll
    for (int off = 32; off > 0; off >>= 1)
        acc += __shfl_down(acc, off);

    __shared__ double wsum[16];
    if ((threadIdx.x & 63) == 0) wsum[threadIdx.x >> 6] = acc;
    __syncthreads();
    if (threadIdx.x == 0) {
        double t = 0.0;
        #pragma unroll
        for (int i = 0; i < 16; ++i) t += wsum[i];
        out[0] = (float)(t / (double)B);
    }
}

extern "C" void kernel_launch(void* const* d_in, const int* in_sizes, int n_in,
                              void* d_out, int out_size, void* d_ws, size_t ws_size,
                              hipStream_t stream) {
    const float* in0 = (const float*)d_in[0];
    const float* in1 = (const float*)d_in[1];
    const int B = in_sizes[0] / (NCH * 512 * 512);   // 32

    unsigned int* ghist = (unsigned int*)d_ws;
    const size_t hist_bytes = (size_t)2 * B * NCH * BINS * sizeof(unsigned int);

    hipMemsetAsync(d_ws, 0, hist_bytes, stream);
    hist_kernel<<<2 * B * BPI, THREADS, 0, stream>>>(in0, in1, ghist, B);
    chi_kernel<<<1, 1024, 0, stream>>>(ghist, (float*)d_out, B);
}